// Round 1
// baseline (117039.270 us; speedup 1.0000x reference)
//
#include <hip/hip_runtime.h>

typedef unsigned short u16;
typedef unsigned int   u32;

// Problem dims
constexpr int SS  = 700;   // seq
constexpr int NB  = 64;    // batch
constexpr int NH  = 400;   // hidden
constexpr int NWG = 200;   // workgroups for the cooperative scan

// ---- workspace layout (float offsets) ----
constexpr size_t OW2  = 0;        // W2cat_h [1600][800]
constexpr size_t OW3  = 1280000;  // W3cat_h [1600][800]
constexpr size_t OWX2 = 2560000;  // Wih2[:, 0:3]  [1600][3]
constexpr size_t OWX3 = 2564800;  // Wih3[:, 0:3]  [1600][3]
constexpr size_t OBS1 = 2569600;  // bih1+bhh1 [1600]
constexpr size_t OBS2 = 2571200;
constexpr size_t OBS3 = 2572800;
constexpr size_t OWH  = 2574400;  // head weights (3-block-summed) [121][400]
constexpr size_t OBH  = 2622800;  // head biases [121] (padded)
constexpr size_t OSB  = 2622928;  // state buffer [2][1200][64]  (h1,h2,h3 transposed, double-buffered)
constexpr size_t OCT  = 2776528;  // cell states [3][400][64]
constexpr size_t OXB  = 2853328;  // x staging [2][3][64]
constexpr size_t OBAR = 2853712;  // barrier cnt,gen (2 x u32)
constexpr size_t OH3F = 2853728;  // H3 bf16 [700][64][400]  (as u16)

// ---- output layout (float offsets in d_out) ----
constexpr size_t OE   = 0;
constexpr size_t OPI  = 44800;
constexpr size_t OMU1 = 940800;
constexpr size_t OMU2 = 1836800;
constexpr size_t OSG1 = 2732800;
constexpr size_t OSG2 = 3628800;
constexpr size_t ORO  = 4524800;
constexpr size_t OST  = 5420800;  // h1,c1,h2,c2,h3,c3 each 25600 (B,H)

struct Ptrs { const float* p[33]; };

__device__ __forceinline__ float sigm(float v) { return 1.f / (1.f + expf(-v)); }

__device__ __forceinline__ u16 f2bf(float f) {
  u32 u = __float_as_uint(f);
  u32 r = (u + 0x7fffu + ((u >> 16) & 1u)) >> 16;  // RNE
  return (u16)r;
}

// ---------------- setup: repack weights, init states, zero barrier ----------------
__global__ __launch_bounds__(256) void setup_kernel(Ptrs in, float* __restrict__ ws)
{
  const size_t TOTAL = 2776715;
  for (size_t idx = (size_t)blockIdx.x * 256 + threadIdx.x; idx < TOTAL;
       idx += (size_t)gridDim.x * 256) {
    size_t i = idx;
    if (i < 1280000) {                       // W2cat_h = [Wih2[:,3:] | Whh2]
      const size_t r = i / 800, k = i % 800;
      ws[OW2 + i] = (k < 400) ? in.p[11][r*403 + 3 + k] : in.p[12][r*400 + (k-400)];
      continue;
    }
    i -= 1280000;
    if (i < 1280000) {                       // W3cat_h = [Wih3[:,3:] | Whh3]
      const size_t r = i / 800, k = i % 800;
      ws[OW3 + i] = (k < 400) ? in.p[15][r*403 + 3 + k] : in.p[16][r*400 + (k-400)];
      continue;
    }
    i -= 1280000;
    if (i < 4800) { ws[OWX2 + i] = in.p[11][(i/3)*403 + (i%3)]; continue; }
    i -= 4800;
    if (i < 4800) { ws[OWX3 + i] = in.p[15][(i/3)*403 + (i%3)]; continue; }
    i -= 4800;
    if (i < 4800) {                          // bias sums (3 cells x 1600, contiguous)
      const size_t c = i / 1600, r = i % 1600;
      ws[OBS1 + i] = in.p[9 + c*4][r] + in.p[10 + c*4][r];
      continue;
    }
    i -= 4800;
    if (i < 48400) {                         // head weights: sum the 3 400-blocks
      const int o = (int)(i / 400), k = (int)(i % 400);
      int src, row;
      if      (o == 0)  { src = 19; row = 0; }
      else if (o < 21)  { src = 21; row = o - 1; }
      else if (o < 41)  { src = 23; row = o - 21; }
      else if (o < 61)  { src = 25; row = o - 41; }
      else if (o < 81)  { src = 27; row = o - 61; }
      else if (o < 101) { src = 29; row = o - 81; }
      else              { src = 31; row = o - 101; }
      const float* W = in.p[src] + (size_t)row * 1200;
      ws[OWH + i] = W[k] + W[400 + k] + W[800 + k];
      continue;
    }
    i -= 48400;
    if (i < 121) {                           // head biases
      const int o = (int)i;
      int src, row;
      if      (o == 0)  { src = 20; row = 0; }
      else if (o < 21)  { src = 22; row = o - 1; }
      else if (o < 41)  { src = 24; row = o - 21; }
      else if (o < 61)  { src = 26; row = o - 41; }
      else if (o < 81)  { src = 28; row = o - 61; }
      else if (o < 101) { src = 30; row = o - 81; }
      else              { src = 32; row = o - 101; }
      ws[OBH + i] = in.p[src][row];
      continue;
    }
    i -= 121;
    if (i < 153600) {                        // initial states, transposed -> SB[1] / cT
      const int half = (int)(i / 76800);     // 0: h, 1: c
      const int r2 = (int)(i % 76800);
      const int cell = r2 / 25600;
      const int rr = r2 % 25600;
      const int j = rr >> 6, b = rr & 63;
      const float v = in.p[1 + cell*2 + half][(size_t)b*400 + j];
      if (half == 0) ws[OSB + 76800 + (size_t)(cell*400 + j)*64 + b] = v;
      else           ws[OCT + (size_t)(cell*400 + j)*64 + b] = v;
      continue;
    }
    i -= 153600;
    if (i < 192) {                           // xbuf[0] = x(t=0) transposed
      const int k = (int)(i >> 6), b = (int)(i & 63);
      ws[OXB + k*64 + b] = in.p[0][(size_t)b*3 + k];
      continue;
    }
    i -= 192;
    if (i < 2) ((u32*)(ws + OBAR))[i] = 0u;  // barrier cnt, gen
  }
}

// ---------------- grid barrier (sense-reversal, agent scope) ----------------
__device__ __forceinline__ void grid_barrier(u32* bar)
{
  __syncthreads();
  if (threadIdx.x == 0) {
    u32 g = __hip_atomic_load(bar + 1, __ATOMIC_RELAXED, __HIP_MEMORY_SCOPE_AGENT);
    u32 old = __hip_atomic_fetch_add(bar, 1u, __ATOMIC_ACQ_REL, __HIP_MEMORY_SCOPE_AGENT);
    if (old == (u32)(NWG - 1)) {
      __hip_atomic_store(bar, 0u, __ATOMIC_RELAXED, __HIP_MEMORY_SCOPE_AGENT);
      __hip_atomic_store(bar + 1, g + 1u, __ATOMIC_RELEASE, __HIP_MEMORY_SCOPE_AGENT);
    } else {
      while (__hip_atomic_load(bar + 1, __ATOMIC_ACQUIRE, __HIP_MEMORY_SCOPE_AGENT) == g)
        __builtin_amdgcn_s_sleep(1);
    }
  }
  __syncthreads();
}

// ---------------- one LSTM cell phase ----------------
// Wave layout: lane=b. Each WG owns 2 h-columns (j0, j0+1); every wave computes all
// 8 gate-columns (2 j x 4 gates) over its quarter of K, LDS-reduce, waves 0/1 finalize.
template<int KH, int CI>
__device__ __forceinline__ void phase(int t, int p,
    const float* __restrict__ x,
    const float* __restrict__ Wc, const float* __restrict__ Wx, const float* __restrict__ bs,
    float* __restrict__ SB, float* __restrict__ cT, float* __restrict__ xb,
    u16* __restrict__ H3, float (*part)[8][64])
{
  const int lane = threadIdx.x & 63;
  const int wv = threadIdx.x >> 6;
  const int j0 = (int)blockIdx.x * 2;
  constexpr int KQ = KH / 4;
  const int kbeg = wv * KQ;
  // parity of the h-rows this wave reads (double-buffered by timestep parity)
  const int par = (CI == 0) ? (p ^ 1) : ((wv < 2) ? p : (p ^ 1));
  const int physRow = ((CI == 2) ? 400 : 0) + kbeg;
  const float* hp = SB + (size_t)par*76800 + (size_t)physRow*64 + lane;

  const float* wr[8];
#pragma unroll
  for (int jj = 0; jj < 2; ++jj)
#pragma unroll
    for (int g = 0; g < 4; ++g)
      wr[jj*4 + g] = Wc + (size_t)(g*400 + j0 + jj) * KH + kbeg;

  float a[8];
#pragma unroll
  for (int i = 0; i < 8; ++i) a[i] = 0.f;

#pragma unroll 4
  for (int k = 0; k < KQ; ++k) {
    const float v = hp[(size_t)k * 64];
#pragma unroll
    for (int i = 0; i < 8; ++i) a[i] = fmaf(v, wr[i][k], a[i]);
  }

  if (wv == 0) {  // x-part (3 columns), added exactly once
    const float* xs = xb + (t & 1) * 192;
#pragma unroll
    for (int k = 0; k < 3; ++k) {
      const float v = xs[k*64 + lane];
#pragma unroll
      for (int jj = 0; jj < 2; ++jj)
#pragma unroll
        for (int g = 0; g < 4; ++g)
          a[jj*4 + g] = fmaf(v, Wx[(g*400 + j0 + jj)*3 + k], a[jj*4 + g]);
    }
  }

  __syncthreads();          // protect `part` from previous phase's readers
#pragma unroll
  for (int i = 0; i < 8; ++i) part[wv][i][lane] = a[i];
  __syncthreads();

  if (wv < 2) {
    const int j = j0 + wv;
    float gv[4];
#pragma unroll
    for (int g = 0; g < 4; ++g)
      gv[g] = part[0][wv*4+g][lane] + part[1][wv*4+g][lane]
            + part[2][wv*4+g][lane] + part[3][wv*4+g][lane] + bs[g*400 + j];
    float* cp = cT + (size_t)CI*25600 + (size_t)j*64 + lane;
    const float co = *cp;
    const float cn = sigm(gv[1]) * co + sigm(gv[0]) * tanhf(gv[2]);
    const float hn = sigm(gv[3]) * tanhf(cn);
    *cp = cn;
    SB[(size_t)p*76800 + (size_t)(CI*400 + j)*64 + lane] = hn;
    if (CI == 2) H3[(size_t)t*25600 + (size_t)lane*400 + j] = f2bf(hn);
  } else if (CI == 1 && wv == 2 && blockIdx.x == 0) {
    const int tn = t + 1;    // stage x(t+1) into the other parity slot
    if (tn < SS) {
#pragma unroll
      for (int k = 0; k < 3; ++k)
        xb[(tn & 1)*192 + k*64 + lane] = x[((size_t)tn*64 + lane)*3 + k];
    }
  }
}

// ---------------- cooperative scan over 700 timesteps ----------------
__global__ __launch_bounds__(256) void lstm_scan(const float* __restrict__ x,
    const float* __restrict__ Wih1, const float* __restrict__ Whh1, float* __restrict__ ws)
{
  __shared__ float part[4][8][64];
  float* SB = ws + OSB;
  float* cT = ws + OCT;
  float* xb = ws + OXB;
  u16*  H3  = (u16*)(ws + OH3F);
  u32*  bar = (u32*)(ws + OBAR);

  for (int t = 0; t < SS; ++t) {
    const int p = t & 1;
    phase<400, 0>(t, p, x, Whh1,     Wih1,      ws + OBS1, SB, cT, xb, H3, part);
    grid_barrier(bar);
    phase<800, 1>(t, p, x, ws + OW2, ws + OWX2, ws + OBS2, SB, cT, xb, H3, part);
    grid_barrier(bar);
    phase<800, 2>(t, p, x, ws + OW3, ws + OWX3, ws + OBS3, SB, cT, xb, H3, part);
    // no grid barrier needed here: phase1(t+1) touches only parity/row ranges
    // disjoint from phase3(t); block-level __syncthreads inside phase protects LDS.
  }
}

// ---------------- MDN heads ----------------
__device__ __forceinline__ void dot2(const u16* hr,
    const float* __restrict__ w0p, const float* __restrict__ w1p,
    float b0, float b1, float& r0, float& r1)
{
  float a0 = b0, a1 = b1;
  const float2* W0 = (const float2*)w0p;
  const float2* W1 = (const float2*)w1p;
#pragma unroll 2
  for (int m = 0; m < 200; ++m) {
    const u32 u = *(const u32*)(hr + 2*m);
    const float lo = __uint_as_float(u << 16);
    const float hi = __uint_as_float(u & 0xffff0000u);
    const float2 c0 = W0[m], c1 = W1[m];
    a0 = fmaf(hi, c0.y, fmaf(lo, c0.x, a0));
    a1 = fmaf(hi, c1.y, fmaf(lo, c1.x, a1));
  }
  r0 = a0; r1 = a1;
}

__device__ __forceinline__ float dot1(const u16* hr, const float* __restrict__ w0p, float b0)
{
  float a0 = b0;
  const float2* W0 = (const float2*)w0p;
#pragma unroll 2
  for (int m = 0; m < 200; ++m) {
    const u32 u = *(const u32*)(hr + 2*m);
    a0 = fmaf(__uint_as_float(u & 0xffff0000u), W0[m].y,
         fmaf(__uint_as_float(u << 16),        W0[m].x, a0));
  }
  return a0;
}

__global__ __launch_bounds__(256) void heads_kernel(const float* __restrict__ ws,
                                                    float* __restrict__ out)
{
  __shared__ u16 hs[64 * 402];   // stride 402 -> conflict-free pair reads
  const u16*  H3 = (const u16*)(ws + OH3F);
  const float* Wh = ws + OWH;
  const float* bh = ws + OBH;
  const int s = blockIdx.x;
  {
    const int b = threadIdx.x >> 2, q = threadIdx.x & 3;
    const uint2* g = (const uint2*)(H3 + (size_t)s*25600 + b*400 + q*100);
    u32* d = (u32*)(hs + b*402 + q*100);
#pragma unroll
    for (int i = 0; i < 25; ++i) { const uint2 v = g[i]; d[2*i] = v.x; d[2*i+1] = v.y; }
  }
  __syncthreads();
  const int wv = threadIdx.x >> 6, lane = threadIdx.x & 63;
  const u16* hr = hs + lane * 402;
  const size_t bs700 = (size_t)lane * 700 + s;

  if (wv == 0) {                 // e + pi (softmax lane-local)
    out[OE + bs700] = 1.f / (1.f + expf(dot1(hr, Wh, bh[0])));
    float pl[20];
#pragma unroll
    for (int op = 0; op < 10; ++op) {
      float r0, r1;
      dot2(hr, Wh + (size_t)(1 + 2*op)*400, Wh + (size_t)(2 + 2*op)*400,
           bh[1 + 2*op], bh[2 + 2*op], r0, r1);
      pl[2*op] = r0; pl[2*op + 1] = r1;
    }
    float mx = pl[0];
#pragma unroll
    for (int i = 1; i < 20; ++i) mx = fmaxf(mx, pl[i]);
    float sm = 0.f;
#pragma unroll
    for (int i = 0; i < 20; ++i) { pl[i] = expf(pl[i] - mx); sm += pl[i]; }
    const float inv = 1.f / sm;
    float* po = out + OPI + bs700 * 20;
#pragma unroll
    for (int i = 0; i < 20; ++i) po[i] = pl[i] * inv;
  } else if (wv == 1) {          // mu1, mu2
    for (int op = 0; op < 20; ++op) {
      float r0, r1;
      dot2(hr, Wh + (size_t)(21 + 2*op)*400, Wh + (size_t)(22 + 2*op)*400,
           bh[21 + 2*op], bh[22 + 2*op], r0, r1);
      const int o0 = 2*op, o1 = o0 + 1;
      out[(o0 < 20) ? (OMU1 + bs700*20 + o0) : (OMU2 + bs700*20 + o0 - 20)] = r0;
      out[(o1 < 20) ? (OMU1 + bs700*20 + o1) : (OMU2 + bs700*20 + o1 - 20)] = r1;
    }
  } else if (wv == 2) {          // sig1, sig2
    for (int op = 0; op < 20; ++op) {
      float r0, r1;
      dot2(hr, Wh + (size_t)(61 + 2*op)*400, Wh + (size_t)(62 + 2*op)*400,
           bh[61 + 2*op], bh[62 + 2*op], r0, r1);
      const int o0 = 2*op, o1 = o0 + 1;
      out[(o0 < 20) ? (OSG1 + bs700*20 + o0) : (OSG2 + bs700*20 + o0 - 20)] = expf(r0);
      out[(o1 < 20) ? (OSG1 + bs700*20 + o1) : (OSG2 + bs700*20 + o1 - 20)] = expf(r1);
    }
  } else {                       // ro
    for (int op = 0; op < 10; ++op) {
      float r0, r1;
      dot2(hr, Wh + (size_t)(101 + 2*op)*400, Wh + (size_t)(102 + 2*op)*400,
           bh[101 + 2*op], bh[102 + 2*op], r0, r1);
      float* po = out + ORO + bs700 * 20;
      po[2*op] = tanhf(r0); po[2*op + 1] = tanhf(r1);
    }
  }
}

// ---------------- final states (H,B)->(B,H) ----------------
__global__ __launch_bounds__(256) void finals_kernel(const float* __restrict__ ws,
                                                     float* __restrict__ out)
{
  const int idx = blockIdx.x * 256 + threadIdx.x;
  if (idx >= 153600) return;
  const int which = idx / 25600;        // h1,c1,h2,c2,h3,c3
  const int r = idx % 25600;
  const int b = r / 400, j = r % 400;
  const int cell = which >> 1;
  float v;
  if (which & 1) v = ws[OCT + (size_t)(cell*400 + j)*64 + b];
  else           v = ws[OSB + 76800 + (size_t)(cell*400 + j)*64 + b]; // t=699 -> parity 1
  out[OST + (size_t)which*25600 + (size_t)b*400 + j] = v;
}

// ---------------- launch ----------------
extern "C" void kernel_launch(void* const* d_in, const int* in_sizes, int n_in,
                              void* d_out, int out_size, void* d_ws, size_t ws_size,
                              hipStream_t stream)
{
  Ptrs in;
  for (int i = 0; i < 33; ++i) in.p[i] = (const float*)d_in[i];
  float* ws  = (float*)d_ws;
  float* out = (float*)d_out;

  hipLaunchKernelGGL(setup_kernel, dim3(4096), dim3(256), 0, stream, in, ws);

  const float* xp   = in.p[0];
  const float* wih1 = in.p[7];
  const float* whh1 = in.p[8];
  void* kArgs[] = { (void*)&xp, (void*)&wih1, (void*)&whh1, (void*)&ws };
  hipLaunchCooperativeKernel((void*)lstm_scan, dim3(NWG), dim3(256), kArgs, 0, stream);

  hipLaunchKernelGGL(heads_kernel, dim3(SS), dim3(256), 0, stream, (const float*)ws, out);
  hipLaunchKernelGGL(finals_kernel, dim3(600), dim3(256), 0, stream, (const float*)ws, out);
}

// Round 2
// 30926.620 us; speedup vs baseline: 3.7844x; 3.7844x over previous
//
#include <hip/hip_runtime.h>

typedef unsigned short u16;
typedef unsigned int   u32;

constexpr int SS  = 700;
constexpr int NWG = 240;   // 80 per layer

// ---- workspace layout (float offsets) ----
constexpr size_t OWP2 = 0;          // packed W2 [80 jb][200 k4][20 r][4] floats
constexpr size_t OWP3 = 1280000;    // packed W3
constexpr size_t OWX1 = 2560000;    // x-cols [400 j][4 g][3]
constexpr size_t OWX2 = 2564800;
constexpr size_t OWX3 = 2569600;
constexpr size_t OB1  = 2574400;    // bias sums [400 j][4 g]
constexpr size_t OB2  = 2576000;
constexpr size_t OB3  = 2577600;
constexpr size_t OWH  = 2579200;    // head weights (3-block-summed) [121][400]
constexpr size_t OBH  = 2627600;    // head biases (pad 128)
constexpr size_t OSB  = 2627728;    // h states [2 parity][1200 rows][64 b]
constexpr size_t OBAR = 2781344;    // barrier: 16 leaves @ stride 32 dwords, root @512, gen @544 (640 dwords)
constexpr size_t OH3  = 2781984;    // H3 bf16 [700 t][400 j][64 b] as u16

// ---- output layout (float offsets) ----
constexpr size_t OE   = 0;
constexpr size_t OPI  = 44800;
constexpr size_t OMU1 = 940800;
constexpr size_t OMU2 = 1836800;
constexpr size_t OSG1 = 2732800;
constexpr size_t OSG2 = 3628800;
constexpr size_t ORO  = 4524800;
constexpr size_t OST  = 5420800;

struct Ptrs { const float* p[33]; };

__device__ __forceinline__ float sigm(float v) { return 1.f / (1.f + expf(-v)); }

__device__ __forceinline__ u16 f2bf(float f) {
  u32 u = __float_as_uint(f);
  return (u16)((u + 0x7fffu + ((u >> 16) & 1u)) >> 16);
}

// ---------------- setup ----------------
__global__ __launch_bounds__(256) void setup_kernel(Ptrs in, float* __restrict__ ws)
{
  const size_t TOTAL = 2705161;
  for (size_t idx = (size_t)blockIdx.x * 256 + threadIdx.x; idx < TOTAL;
       idx += (size_t)gridDim.x * 256) {
    size_t i = idx;
    if (i < 1280000) {                       // WP2: ((jb*200+k4)*20+r)*4+u
      const int u = (int)(i & 3); size_t q = i >> 2;
      const int r = (int)(q % 20); q /= 20;
      const int k4 = (int)(q % 200); const int jb = (int)(q / 200);
      const int grow = (r & 3) * 400 + jb * 5 + (r >> 2);
      const int k = k4 * 4 + u;
      ws[OWP2 + i] = (k < 400) ? in.p[11][(size_t)grow * 403 + 3 + k]
                               : in.p[12][(size_t)grow * 400 + (k - 400)];
      continue;
    }
    i -= 1280000;
    if (i < 1280000) {                       // WP3
      const int u = (int)(i & 3); size_t q = i >> 2;
      const int r = (int)(q % 20); q /= 20;
      const int k4 = (int)(q % 200); const int jb = (int)(q / 200);
      const int grow = (r & 3) * 400 + jb * 5 + (r >> 2);
      const int k = k4 * 4 + u;
      ws[OWP3 + i] = (k < 400) ? in.p[15][(size_t)grow * 403 + 3 + k]
                               : in.p[16][(size_t)grow * 400 + (k - 400)];
      continue;
    }
    i -= 1280000;
    if (i < 14400) {                         // x-col weights, 3 layers x [j][g][3]
      const int l = (int)(i / 4800); const int rem = (int)(i % 4800);
      const int dk = rem % 3; const int q = rem / 3;
      const int g = q & 3; const int j = q >> 2;
      const int grow = g * 400 + j;
      ws[OWX1 + i] = (l == 0) ? in.p[7][(size_t)grow * 3 + dk]
                              : in.p[l == 1 ? 11 : 15][(size_t)grow * 403 + dk];
      continue;
    }
    i -= 14400;
    if (i < 4800) {                          // bias sums [l][j][g]
      const int l = (int)(i / 1600); const int rem = (int)(i % 1600);
      const int g = rem & 3; const int j = rem >> 2;
      const int grow = g * 400 + j;
      ws[OB1 + i] = in.p[9 + 4 * l][grow] + in.p[10 + 4 * l][grow];
      continue;
    }
    i -= 4800;
    if (i < 48400) {                         // head weights: sum 3 blocks
      const int o = (int)(i / 400), k = (int)(i % 400);
      int src, row;
      if      (o == 0)  { src = 19; row = 0; }
      else if (o < 21)  { src = 21; row = o - 1; }
      else if (o < 41)  { src = 23; row = o - 21; }
      else if (o < 61)  { src = 25; row = o - 41; }
      else if (o < 81)  { src = 27; row = o - 61; }
      else if (o < 101) { src = 29; row = o - 81; }
      else              { src = 31; row = o - 101; }
      const float* W = in.p[src] + (size_t)row * 1200;
      ws[OWH + i] = W[k] + W[400 + k] + W[800 + k];
      continue;
    }
    i -= 48400;
    if (i < 121) {                           // head biases
      const int o = (int)i;
      int src, row;
      if      (o == 0)  { src = 20; row = 0; }
      else if (o < 21)  { src = 22; row = o - 1; }
      else if (o < 41)  { src = 24; row = o - 21; }
      else if (o < 61)  { src = 26; row = o - 41; }
      else if (o < 81)  { src = 28; row = o - 61; }
      else if (o < 101) { src = 30; row = o - 81; }
      else              { src = 32; row = o - 101; }
      ws[OBH + i] = in.p[src][row];
      continue;
    }
    i -= 121;
    if (i < 76800) {                         // initial h states (parity per layer)
      const int cell = (int)(i / 25600);
      const int rr = (int)(i % 25600);
      const int j = rr >> 6, b = rr & 63;
      const int par = (cell == 1) ? 0 : 1;   // h1->p1, h2->p0, h3->p1
      ws[OSB + (size_t)par * 76800 + (size_t)(cell * 400 + j) * 64 + b] =
          in.p[1 + cell * 2][(size_t)b * 400 + j];
      continue;
    }
    i -= 76800;
    if (i < 640) ((u32*)(ws + OBAR))[i] = 0u;
  }
}

// ---------------- grid barrier (tree arrival, relaxed spin + fences) ----------------
__device__ __forceinline__ void grid_barrier(u32* bar)
{
  __syncthreads();
  if (threadIdx.x == 0) {
    u32* leaf = bar + (blockIdx.x & 15) * 32;
    u32* root = bar + 512;
    u32* gen  = bar + 544;
    const u32 g = __hip_atomic_load(gen, __ATOMIC_RELAXED, __HIP_MEMORY_SCOPE_AGENT);
    __builtin_amdgcn_fence(__ATOMIC_RELEASE, "agent");   // flush h-writes to coherence point
    const u32 lo = __hip_atomic_fetch_add(leaf, 1u, __ATOMIC_RELAXED, __HIP_MEMORY_SCOPE_AGENT);
    if (lo == 14u) {
      __hip_atomic_store(leaf, 0u, __ATOMIC_RELAXED, __HIP_MEMORY_SCOPE_AGENT);
      const u32 ro = __hip_atomic_fetch_add(root, 1u, __ATOMIC_RELEASE, __HIP_MEMORY_SCOPE_AGENT);
      if (ro == 15u) {
        __hip_atomic_store(root, 0u, __ATOMIC_RELAXED, __HIP_MEMORY_SCOPE_AGENT);
        __hip_atomic_store(gen, g + 1u, __ATOMIC_RELEASE, __HIP_MEMORY_SCOPE_AGENT);
      }
    }
    while (__hip_atomic_load(gen, __ATOMIC_RELAXED, __HIP_MEMORY_SCOPE_AGENT) == g)
      __builtin_amdgcn_s_sleep(2);
    __builtin_amdgcn_fence(__ATOMIC_ACQUIRE, "agent");   // one invalidate on exit
  }
  __syncthreads();
}

// ---------------- scan body, specialized per layer ----------------
template<int LAYER>
__device__ __forceinline__ void scan_body(
    const float* __restrict__ x, const float* __restrict__ Whh1,
    const float* __restrict__ cinit, float* __restrict__ ws, float* __restrict__ out,
    float (*part)[20][64])
{
  const int wg   = blockIdx.x;
  const int jb   = wg - LAYER * 80;
  const int j0   = jb * 5;
  const int lane = threadIdx.x & 63;
  const int wv   = __builtin_amdgcn_readfirstlane((int)(threadIdx.x >> 6));

  float* SB = ws + OSB;
  u16*  H3  = (u16*)(ws + OH3);
  u32*  bar = (u32*)(ws + OBAR);

  // finalize-wave constants (waves 0..4 own j = j0+wv)
  float xw[12], bias[4], cr = 0.f;
  const int j = j0 + wv;
  if (wv < 5) {
    const size_t OWXl = (LAYER == 0) ? OWX1 : (LAYER == 1) ? OWX2 : OWX3;
    const size_t OBl  = (LAYER == 0) ? OB1  : (LAYER == 1) ? OB2  : OB3;
#pragma unroll
    for (int g = 0; g < 4; ++g) {
#pragma unroll
      for (int dk = 0; dk < 3; ++dk) xw[g * 3 + dk] = ws[OWXl + ((size_t)j * 4 + g) * 3 + dk];
      bias[g] = ws[OBl + (size_t)j * 4 + g];
    }
    cr = cinit[(size_t)lane * 400 + j];
  }

  // compute-wave weight streams
  const float2* wr2[20];
  const float4* wp0 = nullptr;
  int inrow0;
  if (LAYER == 0) {
    inrow0 = wv * 50;
#pragma unroll
    for (int r = 0; r < 20; ++r)
      wr2[r] = (const float2*)(Whh1 + (size_t)((r & 3) * 400 + j0 + (r >> 2)) * 400 + inrow0);
  } else {
    inrow0 = (LAYER == 2 ? 400 : 0) + wv * 100;
    wp0 = (const float4*)(ws + ((LAYER == 1) ? OWP2 : OWP3)) + ((size_t)jb * 200 + wv * 25) * 20;
  }

  for (int n = 0; n < 702; ++n) {
    const int p = n & 1;
    const int t = n - LAYER;
    const bool active = (t >= 0) && (t < SS);
    if (active) {
      float acc[20];
#pragma unroll
      for (int r = 0; r < 20; ++r) acc[r] = 0.f;
      const float* hp = SB + (size_t)(p ^ 1) * 76800 + (size_t)inrow0 * 64 + lane;
      if (LAYER == 0) {
        float h0 = hp[0], h1v = hp[64];
        hp += 128;
        for (int kc = 0; kc < 25; ++kc) {
          float n0 = 0.f, n1 = 0.f;
          if (kc < 24) { n0 = hp[0]; n1 = hp[64]; hp += 128; }
#pragma unroll
          for (int r = 0; r < 20; ++r) {
            const float2 w = wr2[r][kc];
            acc[r] = fmaf(h1v, w.y, fmaf(h0, w.x, acc[r]));
          }
          h0 = n0; h1v = n1;
        }
      } else {
        const float4* wp = wp0;
        float h0 = hp[0], h1v = hp[64], h2v = hp[128], h3v = hp[192];
        hp += 256;
        for (int kc = 0; kc < 25; ++kc) {
          float n0 = 0.f, n1 = 0.f, n2 = 0.f, n3 = 0.f;
          if (kc < 24) { n0 = hp[0]; n1 = hp[64]; n2 = hp[128]; n3 = hp[192]; hp += 256; }
#pragma unroll
          for (int r = 0; r < 20; ++r) {
            const float4 w = wp[r];
            acc[r] = fmaf(h3v, w.w, fmaf(h2v, w.z, fmaf(h1v, w.y, fmaf(h0, w.x, acc[r]))));
          }
          wp += 20;
          h0 = n0; h1v = n1; h2v = n2; h3v = n3;
        }
      }
#pragma unroll
      for (int r = 0; r < 20; ++r) part[wv][r][lane] = acc[r];
    }
    __syncthreads();
    if (active && wv < 5) {
      float gv[4];
#pragma unroll
      for (int g = 0; g < 4; ++g) {
        float s = bias[g];
#pragma unroll
        for (int w8 = 0; w8 < 8; ++w8) s += part[w8][wv * 4 + g][lane];
        gv[g] = s;
      }
      const float* xp = x + (size_t)t * 192 + lane * 3;
      const float x0 = xp[0], x1 = xp[1], x2 = xp[2];
#pragma unroll
      for (int g = 0; g < 4; ++g)
        gv[g] += x0 * xw[g * 3] + x1 * xw[g * 3 + 1] + x2 * xw[g * 3 + 2];
      const float fi = sigm(gv[0]), ff = sigm(gv[1]);
      const float gg = tanhf(gv[2]), oo = sigm(gv[3]);
      const float cn = ff * cr + fi * gg;
      const float hn = oo * tanhf(cn);
      cr = cn;
      SB[(size_t)p * 76800 + (size_t)(LAYER * 400 + j) * 64 + lane] = hn;
      if (LAYER == 2) H3[((size_t)t * 400 + j) * 64 + lane] = f2bf(hn);
      if (t == SS - 1) {
        out[OST + (size_t)(LAYER * 2) * 25600     + (size_t)lane * 400 + j] = hn;
        out[OST + (size_t)(LAYER * 2 + 1) * 25600 + (size_t)lane * 400 + j] = cn;
      }
    }
    grid_barrier(bar);
  }
}

__global__ __launch_bounds__(512, 2) void lstm_scan(
    const float* __restrict__ x, const float* __restrict__ Whh1,
    const float* __restrict__ c1p, const float* __restrict__ c2p,
    const float* __restrict__ c3p, float* __restrict__ ws, float* __restrict__ out)
{
  __shared__ float part[8][20][64];
  if (blockIdx.x < 80)       scan_body<0>(x, Whh1, c1p, ws, out, part);
  else if (blockIdx.x < 160) scan_body<1>(x, Whh1, c2p, ws, out, part);
  else                       scan_body<2>(x, Whh1, c3p, ws, out, part);
}

// ---------------- MDN heads ----------------
__device__ __forceinline__ void dot2(const u16* hr,
    const float* __restrict__ w0p, const float* __restrict__ w1p,
    float b0, float b1, float& r0, float& r1)
{
  float a0 = b0, a1 = b1;
  const float2* W0 = (const float2*)w0p;
  const float2* W1 = (const float2*)w1p;
#pragma unroll 2
  for (int m = 0; m < 200; ++m) {
    const u32 u = *(const u32*)(hr + 2 * m);
    const float lo = __uint_as_float(u << 16);
    const float hi = __uint_as_float(u & 0xffff0000u);
    const float2 c0 = W0[m], c1 = W1[m];
    a0 = fmaf(hi, c0.y, fmaf(lo, c0.x, a0));
    a1 = fmaf(hi, c1.y, fmaf(lo, c1.x, a1));
  }
  r0 = a0; r1 = a1;
}

__device__ __forceinline__ float dot1(const u16* hr, const float* __restrict__ w0p, float b0)
{
  float a0 = b0;
  const float2* W0 = (const float2*)w0p;
#pragma unroll 2
  for (int m = 0; m < 200; ++m) {
    const u32 u = *(const u32*)(hr + 2 * m);
    a0 = fmaf(__uint_as_float(u & 0xffff0000u), W0[m].y,
         fmaf(__uint_as_float(u << 16),         W0[m].x, a0));
  }
  return a0;
}

__global__ __launch_bounds__(256) void heads_kernel(const float* __restrict__ ws,
                                                    float* __restrict__ out)
{
  __shared__ u16 hs[64 * 402];
  const u16*  H3 = (const u16*)(ws + OH3);
  const float* Wh = ws + OWH;
  const float* bh = ws + OBH;
  const int s = blockIdx.x;
  const int wv = threadIdx.x >> 6, lane = threadIdx.x & 63;
  const u16* H3t = H3 + (size_t)s * 25600;   // [j][b]
  for (int q = 0; q < 100; ++q) {
    const int jq = wv * 100 + q;
    hs[lane * 402 + jq] = H3t[(size_t)jq * 64 + lane];
  }
  __syncthreads();
  const u16* hr = hs + lane * 402;
  const size_t bs700 = (size_t)lane * 700 + s;

  if (wv == 0) {
    out[OE + bs700] = 1.f / (1.f + expf(dot1(hr, Wh, bh[0])));
    float pl[20];
#pragma unroll
    for (int op = 0; op < 10; ++op) {
      float r0, r1;
      dot2(hr, Wh + (size_t)(1 + 2 * op) * 400, Wh + (size_t)(2 + 2 * op) * 400,
           bh[1 + 2 * op], bh[2 + 2 * op], r0, r1);
      pl[2 * op] = r0; pl[2 * op + 1] = r1;
    }
    float mx = pl[0];
#pragma unroll
    for (int i = 1; i < 20; ++i) mx = fmaxf(mx, pl[i]);
    float sm = 0.f;
#pragma unroll
    for (int i = 0; i < 20; ++i) { pl[i] = expf(pl[i] - mx); sm += pl[i]; }
    const float inv = 1.f / sm;
    float* po = out + OPI + bs700 * 20;
#pragma unroll
    for (int i = 0; i < 20; ++i) po[i] = pl[i] * inv;
  } else if (wv == 1) {
    for (int op = 0; op < 20; ++op) {
      float r0, r1;
      dot2(hr, Wh + (size_t)(21 + 2 * op) * 400, Wh + (size_t)(22 + 2 * op) * 400,
           bh[21 + 2 * op], bh[22 + 2 * op], r0, r1);
      const int o0 = 2 * op, o1 = o0 + 1;
      out[(o0 < 20) ? (OMU1 + bs700 * 20 + o0) : (OMU2 + bs700 * 20 + o0 - 20)] = r0;
      out[(o1 < 20) ? (OMU1 + bs700 * 20 + o1) : (OMU2 + bs700 * 20 + o1 - 20)] = r1;
    }
  } else if (wv == 2) {
    for (int op = 0; op < 20; ++op) {
      float r0, r1;
      dot2(hr, Wh + (size_t)(61 + 2 * op) * 400, Wh + (size_t)(62 + 2 * op) * 400,
           bh[61 + 2 * op], bh[62 + 2 * op], r0, r1);
      const int o0 = 2 * op, o1 = o0 + 1;
      out[(o0 < 20) ? (OSG1 + bs700 * 20 + o0) : (OSG2 + bs700 * 20 + o0 - 20)] = expf(r0);
      out[(o1 < 20) ? (OSG1 + bs700 * 20 + o1) : (OSG2 + bs700 * 20 + o1 - 20)] = expf(r1);
    }
  } else {
    for (int op = 0; op < 10; ++op) {
      float r0, r1;
      dot2(hr, Wh + (size_t)(101 + 2 * op) * 400, Wh + (size_t)(102 + 2 * op) * 400,
           bh[101 + 2 * op], bh[102 + 2 * op], r0, r1);
      float* po = out + ORO + bs700 * 20;
      po[2 * op] = tanhf(r0); po[2 * op + 1] = tanhf(r1);
    }
  }
}

// ---------------- launch ----------------
extern "C" void kernel_launch(void* const* d_in, const int* in_sizes, int n_in,
                              void* d_out, int out_size, void* d_ws, size_t ws_size,
                              hipStream_t stream)
{
  Ptrs in;
  for (int i = 0; i < 33; ++i) in.p[i] = (const float*)d_in[i];
  float* ws  = (float*)d_ws;
  float* out = (float*)d_out;

  hipLaunchKernelGGL(setup_kernel, dim3(4096), dim3(256), 0, stream, in, ws);

  const float* xp   = in.p[0];
  const float* whh1 = in.p[8];
  const float* c1p  = in.p[2];
  const float* c2p  = in.p[4];
  const float* c3p  = in.p[6];
  void* kArgs[] = { (void*)&xp, (void*)&whh1, (void*)&c1p, (void*)&c2p, (void*)&c3p,
                    (void*)&ws, (void*)&out };
  hipLaunchCooperativeKernel((void*)lstm_scan, dim3(NWG), dim3(512), kArgs, 0, stream);

  hipLaunchKernelGGL(heads_kernel, dim3(SS), dim3(256), 0, stream, (const float*)ws, out);
}

// Round 3
// 14652.032 us; speedup vs baseline: 7.9879x; 2.1107x over previous
//
#include <hip/hip_runtime.h>

typedef unsigned short u16;
typedef unsigned int   u32;

constexpr int SS  = 700;
constexpr int NWG = 250;   // 50 L1 + 100 L2 + 100 L3

// ---- workspace layout (float offsets) ----
constexpr size_t OWP1 = 0;         // packed W1 [50 jb][8 wv][25 kc][32 r][2]
constexpr size_t OWP2 = 640000;    // packed W2 [100 jb][8 wv][25 kc][16 r][4]
constexpr size_t OWP3 = 1920000;   // packed W3
constexpr size_t OWH  = 3200000;   // head weights (3-block-summed) [121][400]
constexpr size_t OBH  = 3248400;   // head biases (pad to 128)
constexpr size_t OSB  = 3248528;   // h states [2 parity][1200 rows][64 b]
constexpr size_t OBAR = 3402128;   // barrier: 16 leaves @ stride 32, root @512, gen @544
constexpr size_t OH3  = 3402768;   // H3 bf16 [700 t][400 j][64 b] as u16

// ---- output layout (float offsets) ----
constexpr size_t OE   = 0;
constexpr size_t OPI  = 44800;
constexpr size_t OMU1 = 940800;
constexpr size_t OMU2 = 1836800;
constexpr size_t OSG1 = 2732800;
constexpr size_t OSG2 = 3628800;
constexpr size_t ORO  = 4524800;
constexpr size_t OST  = 5420800;

struct Ptrs { const float* p[33]; };

__device__ __forceinline__ float sigm(float v) { return 1.f / (1.f + expf(-v)); }

__device__ __forceinline__ u16 f2bf(float f) {
  u32 u = __float_as_uint(f);
  return (u16)((u + 0x7fffu + ((u >> 16) & 1u)) >> 16);
}

// ---------------- setup ----------------
__global__ __launch_bounds__(256) void setup_kernel(Ptrs in, float* __restrict__ ws)
{
  const size_t TOTAL = 3325961;
  for (size_t idx = (size_t)blockIdx.x * 256 + threadIdx.x; idx < TOTAL;
       idx += (size_t)gridDim.x * 256) {
    size_t i = idx;
    if (i < 640000) {                        // WP1 [jb][wv][kc][32 r][2]
      const int jb = (int)(i / 12800); size_t rem = i % 12800;
      const int u = (int)(rem & 1); size_t q = rem >> 1;
      const int r = (int)(q % 32); q /= 32;
      const int kc = (int)(q % 25); const int wv = (int)(q / 25);
      const int k = wv * 50 + kc * 2 + u;
      const int grow = (r & 3) * 400 + jb * 8 + (r >> 2);
      ws[OWP1 + i] = in.p[8][(size_t)grow * 400 + k];
      continue;
    }
    i -= 640000;
    if (i < 1280000) {                       // WP2 [jb][wv][kc][16 r][4]
      const int jb = (int)(i / 12800); size_t rem = i % 12800;
      const int u = (int)(rem & 3); size_t q = rem >> 2;
      const int r = (int)(q % 16); q /= 16;
      const int kc = (int)(q % 25); const int wv = (int)(q / 25);
      const int k = wv * 100 + kc * 4 + u;
      const int grow = (r & 3) * 400 + jb * 4 + (r >> 2);
      ws[OWP2 + i] = (k < 400) ? in.p[11][(size_t)grow * 403 + 3 + k]
                               : in.p[12][(size_t)grow * 400 + (k - 400)];
      continue;
    }
    i -= 1280000;
    if (i < 1280000) {                       // WP3
      const int jb = (int)(i / 12800); size_t rem = i % 12800;
      const int u = (int)(rem & 3); size_t q = rem >> 2;
      const int r = (int)(q % 16); q /= 16;
      const int kc = (int)(q % 25); const int wv = (int)(q / 25);
      const int k = wv * 100 + kc * 4 + u;
      const int grow = (r & 3) * 400 + jb * 4 + (r >> 2);
      ws[OWP3 + i] = (k < 400) ? in.p[15][(size_t)grow * 403 + 3 + k]
                               : in.p[16][(size_t)grow * 400 + (k - 400)];
      continue;
    }
    i -= 1280000;
    if (i < 48400) {                         // head weights: sum 3 blocks
      const int o = (int)(i / 400), k = (int)(i % 400);
      int src, row;
      if      (o == 0)  { src = 19; row = 0; }
      else if (o < 21)  { src = 21; row = o - 1; }
      else if (o < 41)  { src = 23; row = o - 21; }
      else if (o < 61)  { src = 25; row = o - 41; }
      else if (o < 81)  { src = 27; row = o - 61; }
      else if (o < 101) { src = 29; row = o - 81; }
      else              { src = 31; row = o - 101; }
      const float* W = in.p[src] + (size_t)row * 1200;
      ws[OWH + i] = W[k] + W[400 + k] + W[800 + k];
      continue;
    }
    i -= 48400;
    if (i < 121) {                           // head biases
      const int o = (int)i;
      int src, row;
      if      (o == 0)  { src = 20; row = 0; }
      else if (o < 21)  { src = 22; row = o - 1; }
      else if (o < 41)  { src = 24; row = o - 21; }
      else if (o < 61)  { src = 26; row = o - 41; }
      else if (o < 81)  { src = 28; row = o - 61; }
      else if (o < 101) { src = 30; row = o - 81; }
      else              { src = 32; row = o - 101; }
      ws[OBH + i] = in.p[src][row];
      continue;
    }
    i -= 121;
    if (i < 76800) {                         // initial h states
      const int cell = (int)(i / 25600);
      const int rr = (int)(i % 25600);
      const int j = rr >> 6, b = rr & 63;
      const int par = (cell == 1) ? 0 : 1;   // h1->p1, h2->p0, h3->p1
      ws[OSB + (size_t)par * 76800 + (size_t)(cell * 400 + j) * 64 + b] =
          in.p[1 + cell * 2][(size_t)b * 400 + j];
      continue;
    }
    i -= 76800;
    if (i < 640) ((u32*)(ws + OBAR))[i] = 0u;
  }
}

// ---------------- grid barrier (16-leaf tree, per-leaf thresholds) ----------------
__device__ __forceinline__ void grid_barrier(u32* bar)
{
  __syncthreads();
  if (threadIdx.x == 0) {
    const int lf = (int)(blockIdx.x >> 4);          // 0..15; leaf 15 has 10 WGs
    u32* leaf = bar + lf * 32;
    u32* root = bar + 512;
    u32* gen  = bar + 544;
    const u32 thr = (lf < 15) ? 15u : 9u;
    const u32 g = __hip_atomic_load(gen, __ATOMIC_RELAXED, __HIP_MEMORY_SCOPE_AGENT);
    __builtin_amdgcn_fence(__ATOMIC_RELEASE, "agent");
    const u32 lo = __hip_atomic_fetch_add(leaf, 1u, __ATOMIC_RELAXED, __HIP_MEMORY_SCOPE_AGENT);
    if (lo == thr) {
      __hip_atomic_store(leaf, 0u, __ATOMIC_RELAXED, __HIP_MEMORY_SCOPE_AGENT);
      const u32 ro = __hip_atomic_fetch_add(root, 1u, __ATOMIC_RELEASE, __HIP_MEMORY_SCOPE_AGENT);
      if (ro == 15u) {
        __hip_atomic_store(root, 0u, __ATOMIC_RELAXED, __HIP_MEMORY_SCOPE_AGENT);
        __hip_atomic_store(gen, g + 1u, __ATOMIC_RELEASE, __HIP_MEMORY_SCOPE_AGENT);
      }
    }
    while (__hip_atomic_load(gen, __ATOMIC_RELAXED, __HIP_MEMORY_SCOPE_AGENT) == g)
      __builtin_amdgcn_s_sleep(2);
    __builtin_amdgcn_fence(__ATOMIC_ACQUIRE, "agent");
  }
  __syncthreads();
}

// ---------------- scan body ----------------
template<int LAYER>
__device__ __forceinline__ void scan_body(Ptrs in, float* __restrict__ ws,
                                          float* __restrict__ out, float* __restrict__ smem)
{
  constexpr int JPW   = (LAYER == 0) ? 8 : 4;       // j per WG = finalize waves
  constexpr int NR    = JPW * 4;                    // (j,g) rows per WG
  constexpr int KPW   = (LAYER == 0) ? 50 : 100;    // k per wave
  constexpr int WGOFF = (LAYER == 0) ? 0 : ((LAYER == 1) ? 50 : 150);
  constexpr size_t OWP = (LAYER == 0) ? OWP1 : ((LAYER == 1) ? OWP2 : OWP3);

  const int jb   = (int)blockIdx.x - WGOFF;
  const int lane = threadIdx.x & 63;
  const int wv   = __builtin_amdgcn_readfirstlane((int)(threadIdx.x >> 6));

  float* SB  = ws + OSB;
  u16*  H3   = (u16*)(ws + OH3);
  u32*  bar  = (u32*)(ws + OBAR);
  const float* x = in.p[0];
  float* wlds = smem;            // 12800 floats
  float* plds = smem + 12800;    // [8][NR][64]

  // load this WG's weight slice into LDS once
  for (int i = threadIdx.x; i < 12800; i += 512)
    wlds[i] = ws[OWP + (size_t)jb * 12800 + i];

  // finalize-wave constants
  float xw[12], bias[4], cr = 0.f;
  const int j = jb * JPW + wv;
  if (wv < JPW) {
    const float* Wx = (LAYER == 0) ? in.p[7] : ((LAYER == 1) ? in.p[11] : in.p[15]);
    const int xs    = (LAYER == 0) ? 3 : 403;
    const float* b0 = (LAYER == 0) ? in.p[9]  : ((LAYER == 1) ? in.p[13] : in.p[17]);
    const float* b1 = (LAYER == 0) ? in.p[10] : ((LAYER == 1) ? in.p[14] : in.p[18]);
    const float* ci = (LAYER == 0) ? in.p[2]  : ((LAYER == 1) ? in.p[4]  : in.p[6]);
#pragma unroll
    for (int g = 0; g < 4; ++g) {
      const int grow = g * 400 + j;
#pragma unroll
      for (int dk = 0; dk < 3; ++dk) xw[g * 3 + dk] = Wx[(size_t)grow * xs + dk];
      bias[g] = b0[grow] + b1[grow];
    }
    cr = ci[(size_t)lane * 400 + j];
  }
  const int inrow0 = ((LAYER == 2) ? 400 : 0) + wv * KPW;
  __syncthreads();

  for (int n = 0; n < 702; ++n) {
    const int p = n & 1;
    const int t = n - LAYER;
    const bool active = (t >= 0) && (t < SS);
    float x0 = 0.f, x1 = 0.f, x2 = 0.f;
    if (active) {
      // batch h loads (one MALL round-trip, all in flight)
      float h[KPW];
      const float* hp = SB + (size_t)(p ^ 1) * 76800 + (size_t)inrow0 * 64 + lane;
#pragma unroll
      for (int k = 0; k < KPW; ++k) h[k] = hp[(size_t)k * 64];
      if (wv < JPW) {
        const float* xp = x + (size_t)t * 192 + lane * 3;
        x0 = xp[0]; x1 = xp[1]; x2 = xp[2];
      }
      float acc[NR];
#pragma unroll
      for (int r = 0; r < NR; ++r) acc[r] = 0.f;
      if (LAYER == 0) {
        const float2* wq = (const float2*)wlds + (size_t)wv * 800;   // [25][32]
#pragma unroll
        for (int kc = 0; kc < 25; ++kc)
#pragma unroll
          for (int r = 0; r < NR; ++r) {
            const float2 w = wq[kc * 32 + r];
            acc[r] = fmaf(h[kc * 2 + 1], w.y, fmaf(h[kc * 2], w.x, acc[r]));
          }
      } else {
        const float4* wq = (const float4*)wlds + (size_t)wv * 400;   // [25][16]
#pragma unroll
        for (int kc = 0; kc < 25; ++kc)
#pragma unroll
          for (int r = 0; r < NR; ++r) {
            const float4 w = wq[kc * 16 + r];
            acc[r] = fmaf(h[kc * 4 + 3], w.w, fmaf(h[kc * 4 + 2], w.z,
                     fmaf(h[kc * 4 + 1], w.y, fmaf(h[kc * 4 + 0], w.x, acc[r]))));
          }
      }
#pragma unroll
      for (int r = 0; r < NR; ++r) plds[((size_t)wv * NR + r) * 64 + lane] = acc[r];
    }
    __syncthreads();
    if (active && wv < JPW) {
      float gv[4];
#pragma unroll
      for (int g = 0; g < 4; ++g) {
        float s = bias[g];
#pragma unroll
        for (int w8 = 0; w8 < 8; ++w8) s += plds[((size_t)w8 * NR + wv * 4 + g) * 64 + lane];
        gv[g] = s + x0 * xw[g * 3] + x1 * xw[g * 3 + 1] + x2 * xw[g * 3 + 2];
      }
      const float fi = sigm(gv[0]), ff = sigm(gv[1]);
      const float gg = tanhf(gv[2]), oo = sigm(gv[3]);
      const float cn = ff * cr + fi * gg;
      const float hn = oo * tanhf(cn);
      cr = cn;
      SB[(size_t)p * 76800 + (size_t)(LAYER * 400 + j) * 64 + lane] = hn;
      if (LAYER == 2) H3[((size_t)t * 400 + j) * 64 + lane] = f2bf(hn);
      if (t == SS - 1) {
        out[OST + (size_t)(LAYER * 2) * 25600     + (size_t)lane * 400 + j] = hn;
        out[OST + (size_t)(LAYER * 2 + 1) * 25600 + (size_t)lane * 400 + j] = cn;
      }
    }
    grid_barrier(bar);
  }
}

__global__ __launch_bounds__(512, 2) void lstm_scan(Ptrs in, float* __restrict__ ws,
                                                    float* __restrict__ out)
{
  __shared__ float smem[12800 + 8 * 32 * 64];
  if (blockIdx.x < 50)       scan_body<0>(in, ws, out, smem);
  else if (blockIdx.x < 150) scan_body<1>(in, ws, out, smem);
  else                       scan_body<2>(in, ws, out, smem);
}

// ---------------- MDN heads ----------------
__device__ __forceinline__ void dot2(const u16* hr,
    const float* __restrict__ w0p, const float* __restrict__ w1p,
    float b0, float b1, float& r0, float& r1)
{
  float a0 = b0, a1 = b1;
  const float2* W0 = (const float2*)w0p;
  const float2* W1 = (const float2*)w1p;
#pragma unroll 2
  for (int m = 0; m < 200; ++m) {
    const u32 u = *(const u32*)(hr + 2 * m);
    const float lo = __uint_as_float(u << 16);
    const float hi = __uint_as_float(u & 0xffff0000u);
    const float2 c0 = W0[m], c1 = W1[m];
    a0 = fmaf(hi, c0.y, fmaf(lo, c0.x, a0));
    a1 = fmaf(hi, c1.y, fmaf(lo, c1.x, a1));
  }
  r0 = a0; r1 = a1;
}

__device__ __forceinline__ float dot1(const u16* hr, const float* __restrict__ w0p, float b0)
{
  float a0 = b0;
  const float2* W0 = (const float2*)w0p;
#pragma unroll 2
  for (int m = 0; m < 200; ++m) {
    const u32 u = *(const u32*)(hr + 2 * m);
    a0 = fmaf(__uint_as_float(u & 0xffff0000u), W0[m].y,
         fmaf(__uint_as_float(u << 16),         W0[m].x, a0));
  }
  return a0;
}

__global__ __launch_bounds__(256) void heads_kernel(const float* __restrict__ ws,
                                                    float* __restrict__ out)
{
  __shared__ u16 hs[64 * 402];
  const u16*  H3 = (const u16*)(ws + OH3);
  const float* Wh = ws + OWH;
  const float* bh = ws + OBH;
  const int s = blockIdx.x;
  const int wv = threadIdx.x >> 6, lane = threadIdx.x & 63;
  const u16* H3t = H3 + (size_t)s * 25600;   // [j][b]
  for (int q = 0; q < 100; ++q) {
    const int jq = wv * 100 + q;
    hs[lane * 402 + jq] = H3t[(size_t)jq * 64 + lane];
  }
  __syncthreads();
  const u16* hr = hs + lane * 402;
  const size_t bs700 = (size_t)lane * 700 + s;

  if (wv == 0) {
    out[OE + bs700] = 1.f / (1.f + expf(dot1(hr, Wh, bh[0])));
    float pl[20];
#pragma unroll
    for (int op = 0; op < 10; ++op) {
      float r0, r1;
      dot2(hr, Wh + (size_t)(1 + 2 * op) * 400, Wh + (size_t)(2 + 2 * op) * 400,
           bh[1 + 2 * op], bh[2 + 2 * op], r0, r1);
      pl[2 * op] = r0; pl[2 * op + 1] = r1;
    }
    float mx = pl[0];
#pragma unroll
    for (int i = 1; i < 20; ++i) mx = fmaxf(mx, pl[i]);
    float sm = 0.f;
#pragma unroll
    for (int i = 0; i < 20; ++i) { pl[i] = expf(pl[i] - mx); sm += pl[i]; }
    const float inv = 1.f / sm;
    float* po = out + OPI + bs700 * 20;
#pragma unroll
    for (int i = 0; i < 20; ++i) po[i] = pl[i] * inv;
  } else if (wv == 1) {
    for (int op = 0; op < 20; ++op) {
      float r0, r1;
      dot2(hr, Wh + (size_t)(21 + 2 * op) * 400, Wh + (size_t)(22 + 2 * op) * 400,
           bh[21 + 2 * op], bh[22 + 2 * op], r0, r1);
      const int o0 = 2 * op, o1 = o0 + 1;
      out[(o0 < 20) ? (OMU1 + bs700 * 20 + o0) : (OMU2 + bs700 * 20 + o0 - 20)] = r0;
      out[(o1 < 20) ? (OMU1 + bs700 * 20 + o1) : (OMU2 + bs700 * 20 + o1 - 20)] = r1;
    }
  } else if (wv == 2) {
    for (int op = 0; op < 20; ++op) {
      float r0, r1;
      dot2(hr, Wh + (size_t)(61 + 2 * op) * 400, Wh + (size_t)(62 + 2 * op) * 400,
           bh[61 + 2 * op], bh[62 + 2 * op], r0, r1);
      const int o0 = 2 * op, o1 = o0 + 1;
      out[(o0 < 20) ? (OSG1 + bs700 * 20 + o0) : (OSG2 + bs700 * 20 + o0 - 20)] = expf(r0);
      out[(o1 < 20) ? (OSG1 + bs700 * 20 + o1) : (OSG2 + bs700 * 20 + o1 - 20)] = expf(r1);
    }
  } else {
    for (int op = 0; op < 10; ++op) {
      float r0, r1;
      dot2(hr, Wh + (size_t)(101 + 2 * op) * 400, Wh + (size_t)(102 + 2 * op) * 400,
           bh[101 + 2 * op], bh[102 + 2 * op], r0, r1);
      float* po = out + ORO + bs700 * 20;
      po[2 * op] = tanhf(r0); po[2 * op + 1] = tanhf(r1);
    }
  }
}

// ---------------- launch ----------------
extern "C" void kernel_launch(void* const* d_in, const int* in_sizes, int n_in,
                              void* d_out, int out_size, void* d_ws, size_t ws_size,
                              hipStream_t stream)
{
  Ptrs in;
  for (int i = 0; i < 33; ++i) in.p[i] = (const float*)d_in[i];
  float* ws  = (float*)d_ws;
  float* out = (float*)d_out;

  hipLaunchKernelGGL(setup_kernel, dim3(4096), dim3(256), 0, stream, in, ws);

  void* kArgs[] = { (void*)&in, (void*)&ws, (void*)&out };
  hipLaunchCooperativeKernel((void*)lstm_scan, dim3(NWG), dim3(512), kArgs, 0, stream);

  hipLaunchKernelGGL(heads_kernel, dim3(SS), dim3(256), 0, stream, (const float*)ws, out);
}

// Round 7
// 8928.586 us; speedup vs baseline: 13.1084x; 1.6410x over previous
//
#include <hip/hip_runtime.h>

typedef unsigned short u16;
typedef unsigned int   u32;
typedef __attribute__((ext_vector_type(8))) _Float16 f16x8;
typedef __attribute__((ext_vector_type(4))) float    f32x4;

constexpr int SS  = 700;
constexpr int NWG = 150;   // 50 WGs per layer, 8 rows(j) x 64 batch each

// ---- workspace layout (float offsets) ----
constexpr size_t OA1  = 0;        // A-pack L1 [50 jb][2 rt][13 kt][64 lane][8] f16
constexpr size_t OA2  = 332800;   // A-pack L2 [50][2][25][64][8] f16
constexpr size_t OA3  = 972800;   // A-pack L3
constexpr size_t OWH  = 1612800;  // head weights (3-block-summed) [121][400] f32
constexpr size_t OBH  = 1661200;  // head biases (pad 128)
constexpr size_t OSBT = 1661328;  // u16 [2 parity][64 b][1200 k]  (h1|h2|h3, f16)
constexpr size_t OBAR = 1738128;  // barrier: 16 leaves @ stride 32, root @512, gen @544
constexpr size_t OH3  = 1738768;  // u16 [700 t][64 b][400 j]  (f16)

// ---- output layout (float offsets) ----
constexpr size_t OE   = 0;
constexpr size_t OPI  = 44800;
constexpr size_t OMU1 = 940800;
constexpr size_t OMU2 = 1836800;
constexpr size_t OSG1 = 2732800;
constexpr size_t OSG2 = 3628800;
constexpr size_t ORO  = 4524800;
constexpr size_t OST  = 5420800;

struct Ptrs { const float* p[33]; };

__device__ __forceinline__ float sigm(float v) { return 1.f / (1.f + expf(-v)); }

union HU { u16 u; _Float16 h; };

__device__ __forceinline__ u16 f2h(float f) {
  HU c; c.h = (_Float16)f; return c.u;
}
__device__ __forceinline__ float h2f(u16 u) {
  HU c; c.u = u; return (float)c.h;
}

// ---------------- setup: pack MFMA A-fragments, init states ----------------
__device__ __forceinline__ float apack_val(const Ptrs& in, int layer, size_t i, int KT)
{
  const int e = (int)(i & 7); const int lane = (int)((i >> 3) & 63);
  size_t q = i >> 9; const int kt = (int)(q % KT); q /= KT;
  const int rt = (int)(q & 1); const int jb = (int)(q >> 1);
  const int rw = lane & 15; const int g = rw & 3; const int js = rw >> 2;
  const int j = jb * 8 + rt * 4 + js;
  const int grow = g * 400 + j;
  const int kk = kt * 32 + 8 * (lane >> 4) + e;
  if (layer == 0) return (kk < 400) ? in.p[8][(size_t)grow * 400 + kk] : 0.f;
  const float* Wih = (layer == 1) ? in.p[11] : in.p[15];
  const float* Whh = (layer == 1) ? in.p[12] : in.p[16];
  return (kk < 400) ? Wih[(size_t)grow * 403 + 3 + kk]
                    : Whh[(size_t)grow * 400 + (kk - 400)];
}

__global__ __launch_bounds__(256) void setup_kernel(Ptrs in, float* __restrict__ ws)
{
  u16* wsu = (u16*)ws;
  const size_t TOTAL = 3351561;
  for (size_t idx = (size_t)blockIdx.x * 256 + threadIdx.x; idx < TOTAL;
       idx += (size_t)gridDim.x * 256) {
    size_t i = idx;
    if (i < 665600)  { wsu[OA1 * 2 + i] = f2h(apack_val(in, 0, i, 13)); continue; }
    i -= 665600;
    if (i < 1280000) { wsu[OA2 * 2 + i] = f2h(apack_val(in, 1, i, 25)); continue; }
    i -= 1280000;
    if (i < 1280000) { wsu[OA3 * 2 + i] = f2h(apack_val(in, 2, i, 25)); continue; }
    i -= 1280000;
    if (i < 48400) {                         // head weights: sum 3 400-blocks
      const int o = (int)(i / 400), k = (int)(i % 400);
      int src, row;
      if      (o == 0)  { src = 19; row = 0; }
      else if (o < 21)  { src = 21; row = o - 1; }
      else if (o < 41)  { src = 23; row = o - 21; }
      else if (o < 61)  { src = 25; row = o - 41; }
      else if (o < 81)  { src = 27; row = o - 61; }
      else if (o < 101) { src = 29; row = o - 81; }
      else              { src = 31; row = o - 101; }
      const float* W = in.p[src] + (size_t)row * 1200;
      ws[OWH + i] = W[k] + W[400 + k] + W[800 + k];
      continue;
    }
    i -= 48400;
    if (i < 121) {                           // head biases
      const int o = (int)i;
      int src, row;
      if      (o == 0)  { src = 20; row = 0; }
      else if (o < 21)  { src = 22; row = o - 1; }
      else if (o < 41)  { src = 24; row = o - 21; }
      else if (o < 61)  { src = 26; row = o - 41; }
      else if (o < 81)  { src = 28; row = o - 61; }
      else if (o < 101) { src = 30; row = o - 81; }
      else              { src = 32; row = o - 101; }
      ws[OBH + i] = in.p[src][row];
      continue;
    }
    i -= 121;
    if (i < 76800) {                         // initial h states -> SBT (f16)
      const int cell = (int)(i / 25600);
      const int rr = (int)(i % 25600);
      const int j = rr >> 6, b = rr & 63;
      const int par = (cell == 1) ? 0 : 1;   // h1->p1, h2->p0, h3->p1
      wsu[OSBT * 2 + (size_t)par * 76800 + (size_t)b * 1200 + cell * 400 + j] =
          f2h(in.p[1 + cell * 2][(size_t)b * 400 + j]);
      continue;
    }
    i -= 76800;
    if (i < 640) ((u32*)(ws + OBAR))[i] = 0u;
  }
}

// ---------------- grid barrier (16-leaf tree) ----------------
__device__ __forceinline__ void grid_barrier(u32* bar)
{
  __syncthreads();
  if (threadIdx.x == 0) {
    const int lf = (int)(blockIdx.x & 15);          // residues 0..5: 10 WGs, else 9
    u32* leaf = bar + lf * 32;
    u32* root = bar + 512;
    u32* gen  = bar + 544;
    const u32 thr = (lf < 6) ? 9u : 8u;
    const u32 g = __hip_atomic_load(gen, __ATOMIC_RELAXED, __HIP_MEMORY_SCOPE_AGENT);
    __builtin_amdgcn_fence(__ATOMIC_RELEASE, "agent");
    const u32 lo = __hip_atomic_fetch_add(leaf, 1u, __ATOMIC_RELAXED, __HIP_MEMORY_SCOPE_AGENT);
    if (lo == thr) {
      __hip_atomic_store(leaf, 0u, __ATOMIC_RELAXED, __HIP_MEMORY_SCOPE_AGENT);
      const u32 ro = __hip_atomic_fetch_add(root, 1u, __ATOMIC_RELEASE, __HIP_MEMORY_SCOPE_AGENT);
      if (ro == 15u) {
        __hip_atomic_store(root, 0u, __ATOMIC_RELAXED, __HIP_MEMORY_SCOPE_AGENT);
        __hip_atomic_store(gen, g + 1u, __ATOMIC_RELEASE, __HIP_MEMORY_SCOPE_AGENT);
      }
    }
    while (__hip_atomic_load(gen, __ATOMIC_RELAXED, __HIP_MEMORY_SCOPE_AGENT) == g)
      __builtin_amdgcn_s_sleep(2);
    __builtin_amdgcn_fence(__ATOMIC_ACQUIRE, "agent");
  }
  __syncthreads();
}

// ---------------- scan body ----------------
template<int LAYER>
__device__ __forceinline__ void scan_body(Ptrs in, float* __restrict__ ws,
                                          float* __restrict__ out, char* __restrict__ lds)
{
  constexpr int KT   = (LAYER == 0) ? 13 : 25;     // K tiles of 32 (L1 padded 400->416)
  constexpr int RB   = KT * 64 + 16;               // LDS row bytes (+8 f16 pad)
  constexpr int DCH  = KT * 4;                     // 16B data chunks per row
  constexpr int COL0 = (LAYER == 2) ? 400 : 0;     // SBT col origin (f16 idx)
  constexpr int WCOL = LAYER * 400;                // write col base
  constexpr size_t OA = (LAYER == 0) ? OA1 : ((LAYER == 1) ? OA2 : OA3);

  const int jb   = (int)blockIdx.x - 50 * LAYER;
  const int tid  = (int)threadIdx.x;
  const int lane = tid & 63;
  const int wv   = tid >> 6;          // 0..7
  const int rt   = wv >> 2;           // row-tile 0..1
  const int bt   = wv & 3;            // batch-tile 0..3

  u16* SBT = (u16*)(ws + OSBT);
  u16* H3  = (u16*)(ws + OH3);
  u32* bar = (u32*)(ws + OBAR);
  const float* x = in.p[0];

  // this lane's output element (j, b): C layout row = 4*(lane>>4)+reg, col = lane&15
  const int j = jb * 8 + rt * 4 + (lane >> 4);
  const int b = bt * 16 + (lane & 15);

  // finalize constants (per-lane)
  float xw[12], bias[4];
  {
    const float* Wx = (LAYER == 0) ? in.p[7]  : ((LAYER == 1) ? in.p[11] : in.p[15]);
    const int    xs = (LAYER == 0) ? 3 : 403;
    const float* b0 = (LAYER == 0) ? in.p[9]  : ((LAYER == 1) ? in.p[13] : in.p[17]);
    const float* b1 = (LAYER == 0) ? in.p[10] : ((LAYER == 1) ? in.p[14] : in.p[18]);
#pragma unroll
    for (int g = 0; g < 4; ++g) {
      const int grow = g * 400 + j;
#pragma unroll
      for (int dk = 0; dk < 3; ++dk) xw[g * 3 + dk] = Wx[(size_t)grow * xs + dk];
      bias[g] = b0[grow] + b1[grow];
    }
  }
  float cr = ((LAYER == 0) ? in.p[2] : (LAYER == 1) ? in.p[4] : in.p[6])[(size_t)b * 400 + j];

  // A-fragments (weights) -> registers, resident for the whole scan
  f16x8 A[KT];
  {
    const char* ap = (const char*)((u16*)(ws + OA) +
        ((size_t)(jb * 2 + rt) * KT * 64 + lane) * 8);
#pragma unroll
    for (int kt = 0; kt < KT; ++kt)
      A[kt] = *(const f16x8*)(ap + (size_t)kt * 1024);
  }

  const char* bpk = lds + (size_t)b * RB + (lane >> 4) * 16;  // B-frag base for this lane

  for (int n = 0; n < 702; ++n) {
    const int p = n & 1;
    const int t = n - LAYER;
    const bool active = (t >= 0) && (t < SS);
    if (active) {
      // stage h (f16, [b][k]) from SBT[p^1] into LDS [64][RB] via registers.
      // (global_load_lds with an int-cast LDS pointer was silently dropped by
      //  the compiler in R4-R6 -> LDS stayed poison; plain reg staging is safe.)
      const u16* src = SBT + (size_t)(p ^ 1) * 76800 + COL0;
      for (int c = tid; c < 64 * DCH; c += 512) {
        const int brow = c / DCH;
        const int cid  = c % DCH;
        *(uint4*)(lds + (size_t)brow * RB + (size_t)cid * 16) =
            *(const uint4*)(src + (size_t)brow * 1200 + (size_t)cid * 8);
      }
    }
    __syncthreads();
    if (active) {
      const float* xp = x + (size_t)t * 192 + b * 3;
      const float x0 = xp[0], x1 = xp[1], x2 = xp[2];
      f32x4 accA = {0.f, 0.f, 0.f, 0.f};
      f32x4 accB = {0.f, 0.f, 0.f, 0.f};
#pragma unroll
      for (int kt = 0; kt < KT; ++kt) {
        const f16x8 bv = *(const f16x8*)(bpk + kt * 64);
        if (kt & 1) accB = __builtin_amdgcn_mfma_f32_16x16x32_f16(A[kt], bv, accB, 0, 0, 0);
        else        accA = __builtin_amdgcn_mfma_f32_16x16x32_f16(A[kt], bv, accA, 0, 0, 0);
      }
      float gv[4];
#pragma unroll
      for (int g = 0; g < 4; ++g)
        gv[g] = accA[g] + accB[g] + bias[g]
              + x0 * xw[g * 3] + x1 * xw[g * 3 + 1] + x2 * xw[g * 3 + 2];
      const float fi = sigm(gv[0]), ff = sigm(gv[1]);
      const float gg = tanhf(gv[2]), oo = sigm(gv[3]);
      const float cn = ff * cr + fi * gg;
      const float hn = oo * tanhf(cn);
      cr = cn;
      SBT[(size_t)p * 76800 + (size_t)b * 1200 + WCOL + j] = f2h(hn);
      if (LAYER == 2) H3[((size_t)t * 64 + b) * 400 + j] = f2h(hn);
      if (t == SS - 1) {
        out[OST + (size_t)(LAYER * 2) * 25600     + (size_t)b * 400 + j] = hn;
        out[OST + (size_t)(LAYER * 2 + 1) * 25600 + (size_t)b * 400 + j] = cn;
      }
    }
    grid_barrier(bar);
  }
}

// Normal launch (not cooperative): 150 WGs at 1 WG/CU (LDS-limited) on 256 CUs
// are always physically co-resident, which is all the hand-rolled barrier needs.
__global__ __launch_bounds__(512, 2) void lstm_scan(Ptrs in, float* __restrict__ ws,
                                                    float* __restrict__ out)
{
  __shared__ __align__(16) char lds[103424];   // 64 rows x 1616 B (L1 uses 54272)
  if (blockIdx.x < 50)       scan_body<0>(in, ws, out, lds);
  else if (blockIdx.x < 100) scan_body<1>(in, ws, out, lds);
  else                       scan_body<2>(in, ws, out, lds);
}

// ---------------- MDN heads ----------------
__device__ __forceinline__ void dot2(const u16* hr,
    const float* __restrict__ w0p, const float* __restrict__ w1p,
    float b0, float b1, float& r0, float& r1)
{
  float a0 = b0, a1 = b1;
  const float2* W0 = (const float2*)w0p;
  const float2* W1 = (const float2*)w1p;
#pragma unroll 2
  for (int m = 0; m < 200; ++m) {
    const u32 u = *(const u32*)(hr + 2 * m);
    const float lo = h2f((u16)(u & 0xffffu));
    const float hi = h2f((u16)(u >> 16));
    const float2 c0 = W0[m], c1 = W1[m];
    a0 = fmaf(hi, c0.y, fmaf(lo, c0.x, a0));
    a1 = fmaf(hi, c1.y, fmaf(lo, c1.x, a1));
  }
  r0 = a0; r1 = a1;
}

__device__ __forceinline__ float dot1(const u16* hr, const float* __restrict__ w0p, float b0)
{
  float a0 = b0;
  const float2* W0 = (const float2*)w0p;
#pragma unroll 2
  for (int m = 0; m < 200; ++m) {
    const u32 u = *(const u32*)(hr + 2 * m);
    a0 = fmaf(h2f((u16)(u >> 16)),     W0[m].y,
         fmaf(h2f((u16)(u & 0xffffu)), W0[m].x, a0));
  }
  return a0;
}

__global__ __launch_bounds__(256) void heads_kernel(const float* __restrict__ ws,
                                                    float* __restrict__ out)
{
  __shared__ u16 hs[64 * 402];                 // dword stride 201 -> conflict-free
  const u16*  H3 = (const u16*)(ws + OH3);
  const float* Wh = ws + OWH;
  const float* bh = ws + OBH;
  const int s = blockIdx.x;
  const int tid = threadIdx.x;
  {
    const u32* H3r = (const u32*)(H3 + (size_t)s * 25600);   // [b][400 j] rows
    u32* hs32 = (u32*)hs;
    for (int idx = tid; idx < 64 * 200; idx += 256) {
      const int bb = idx / 200, cc = idx % 200;
      hs32[bb * 201 + cc] = H3r[bb * 200 + cc];
    }
  }
  __syncthreads();
  const int wv = tid >> 6, lane = tid & 63;
  const u16* hr = hs + lane * 402;
  const size_t bs700 = (size_t)lane * 700 + s;

  if (wv == 0) {
    out[OE + bs700] = 1.f / (1.f + expf(dot1(hr, Wh, bh[0])));
    float pl[20];
#pragma unroll
    for (int op = 0; op < 10; ++op) {
      float r0, r1;
      dot2(hr, Wh + (size_t)(1 + 2 * op) * 400, Wh + (size_t)(2 + 2 * op) * 400,
           bh[1 + 2 * op], bh[2 + 2 * op], r0, r1);
      pl[2 * op] = r0; pl[2 * op + 1] = r1;
    }
    float mx = pl[0];
#pragma unroll
    for (int i = 1; i < 20; ++i) mx = fmaxf(mx, pl[i]);
    float sm = 0.f;
#pragma unroll
    for (int i = 0; i < 20; ++i) { pl[i] = expf(pl[i] - mx); sm += pl[i]; }
    const float inv = 1.f / sm;
    float* po = out + OPI + bs700 * 20;
#pragma unroll
    for (int i = 0; i < 20; ++i) po[i] = pl[i] * inv;
  } else if (wv == 1) {
    for (int op = 0; op < 20; ++op) {
      float r0, r1;
      dot2(hr, Wh + (size_t)(21 + 2 * op) * 400, Wh + (size_t)(22 + 2 * op) * 400,
           bh[21 + 2 * op], bh[22 + 2 * op], r0, r1);
      const int o0 = 2 * op, o1 = o0 + 1;
      out[(o0 < 20) ? (OMU1 + bs700 * 20 + o0) : (OMU2 + bs700 * 20 + o0 - 20)] = r0;
      out[(o1 < 20) ? (OMU1 + bs700 * 20 + o1) : (OMU2 + bs700 * 20 + o1 - 20)] = r1;
    }
  } else if (wv == 2) {
    for (int op = 0; op < 20; ++op) {
      float r0, r1;
      dot2(hr, Wh + (size_t)(61 + 2 * op) * 400, Wh + (size_t)(62 + 2 * op) * 400,
           bh[61 + 2 * op], bh[62 + 2 * op], r0, r1);
      const int o0 = 2 * op, o1 = o0 + 1;
      out[(o0 < 20) ? (OSG1 + bs700 * 20 + o0) : (OSG2 + bs700 * 20 + o0 - 20)] = expf(r0);
      out[(o1 < 20) ? (OSG1 + bs700 * 20 + o1) : (OSG2 + bs700 * 20 + o1 - 20)] = expf(r1);
    }
  } else {
    for (int op = 0; op < 10; ++op) {
      float r0, r1;
      dot2(hr, Wh + (size_t)(101 + 2 * op) * 400, Wh + (size_t)(102 + 2 * op) * 400,
           bh[101 + 2 * op], bh[102 + 2 * op], r0, r1);
      float* po = out + ORO + bs700 * 20;
      po[2 * op] = tanhf(r0); po[2 * op + 1] = tanhf(r1);
    }
  }
}

// ---------------- launch ----------------
extern "C" void kernel_launch(void* const* d_in, const int* in_sizes, int n_in,
                              void* d_out, int out_size, void* d_ws, size_t ws_size,
                              hipStream_t stream)
{
  Ptrs in;
  for (int i = 0; i < 33; ++i) in.p[i] = (const float*)d_in[i];
  float* ws  = (float*)d_ws;
  float* out = (float*)d_out;

  hipLaunchKernelGGL(setup_kernel, dim3(4096), dim3(256), 0, stream, in, ws);
  hipLaunchKernelGGL(lstm_scan, dim3(NWG), dim3(512), 0, stream, in, ws, out);
  hipLaunchKernelGGL(heads_kernel, dim3(SS), dim3(256), 0, stream, (const float*)ws, out);
}